// Round 4
// baseline (385.639 us; speedup 1.0000x reference)
//
#include <hip/hip_runtime.h>
#include <math.h>

#define B_N 2048
#define KK 128
#define MM 640
#define HS 136    // k-stride (elems) for transposed bf16 B-panels (mult of 8 for b128 align)
#define ZSS 40    // Z row stride (bf16)
#define ALPHA (1.0f/128.0f)
#define VARTHETA 0.1f
#define PMAXV 10.0f
#define BIGV 1000000000.0f

typedef __attribute__((ext_vector_type(8))) short short8;
typedef __attribute__((ext_vector_type(4))) float floatx4;

static __device__ __forceinline__ unsigned short f2bf(float f) {
    unsigned u = __builtin_bit_cast(unsigned, f);
    u += 0x7fffu + ((u >> 16) & 1u);           // RNE
    return (unsigned short)(u >> 16);
}
static __device__ __forceinline__ float bf2f(unsigned short h) {
    unsigned u = ((unsigned)h) << 16;
    return __builtin_bit_cast(float, u);
}

// LDS pool overlays:
//  poolA (10240 B): w1aT (8704, staging->MFMA1)  then  zb (10240, MFMA2->E)
//  poolB (8704 B) : colred (4096, phase1->g1) -> c2T (8704, MFMA1->MFMA2)
//                   -> eT(1360 @0) / dpred(4096 @2048) / diag(512 @6400)
#define POOLA_OFF 0
#define POOLB_OFF 10240
#define POOL_BYTES (10240 + 8704)

// launch_bounds(512,4): VGPR cap 128 — R3's (512,6) cap of ~85 forced ~200MB of
// scratch spills (WRITE_SIZE 9.2->201 MB). If allocator lands <=85 naturally,
// HW still reaches 3 blocks/CU; the bound only guarantees 2.
__global__ __launch_bounds__(512, 4)
void unfold_pocs_kernel(
    const int* __restrict__ num_itr_p, const int* __restrict__ kth_p,
    const float* __restrict__ HW, const float* __restrict__ x0,
    const float* __restrict__ nu3_p, const float* __restrict__ tg_p,
    const float* __restrict__ g1_W0a, const float* __restrict__ g1_W1a,
    const float* __restrict__ g1_W0b, const float* __restrict__ g1_W1b,
    const float* __restrict__ g2_W0a, const float* __restrict__ g2_W1a,
    const float* __restrict__ g2_W0b, const float* __restrict__ g2_W1b,
    float* __restrict__ out)
{
    __shared__ __align__(16) unsigned char pool[POOL_BYTES];
    __shared__ __align__(16) float xb[MM];
    __shared__ __align__(16) float scr8[KK*8];             // SX (phase1->g1), t0 (E->tilde)
    __shared__ __align__(16) float g1w0a[160], g1w1a[160];
    __shared__ __align__(16) float g1w0b[64],  g1w1b[64];
    __shared__ __align__(16) float w0a2b[160], w1a2b[160]; // bottom 5 rows of g2 W0a/W1a
    __shared__ __align__(16) float w0b2[160],  w1b2[160];  // 32x5
    __shared__ float red[16];

    unsigned short* w1aT  = (unsigned short*)(pool + POOLA_OFF);
    unsigned short* zbp   = (unsigned short*)(pool + POOLA_OFF);
    float*          colred= (float*)(pool + POOLB_OFF);
    unsigned short* c2T   = (unsigned short*)(pool + POOLB_OFF);
    unsigned short* eT    = (unsigned short*)(pool + POOLB_OFF);
    float*          dpred = (float*)(pool + POOLB_OFF + 2048);
    float*          diagl = (float*)(pool + POOLB_OFF + 6400);

    const int t = threadIdx.x;
    const int b = blockIdx.x;
    const float* HWb = HW + (size_t)b * (KK*KK);

    const int wv = t >> 6, lane = t & 63, quad = lane >> 4, lr = lane & 15;
    const int arow = wv*16 + lr;

    // ---------- staging ----------
    short8 A[4];                                // hw A-fragments, straight from HBM
    #pragma unroll
    for (int kt = 0; kt < 4; ++kt) {
        float4 f0 = *(const float4*)(HWb + arow*KK + kt*32 + quad*8);
        float4 f1 = *(const float4*)(HWb + arow*KK + kt*32 + quad*8 + 4);
        short8 a;
        a[0]=(short)f2bf(f0.x); a[1]=(short)f2bf(f0.y); a[2]=(short)f2bf(f0.z); a[3]=(short)f2bf(f0.w);
        a[4]=(short)f2bf(f1.x); a[5]=(short)f2bf(f1.y); a[6]=(short)f2bf(f1.z); a[7]=(short)f2bf(f1.w);
        A[kt] = a;
    }
    {   // W1a_top (128x32) -> transposed bf16, k-fastest (coalesced global, b128 LDS writes)
        const int n = t & 31, seg = t >> 5;     // 16 segs of 8 k
        unsigned short tmp[8];
        #pragma unroll
        for (int i = 0; i < 8; ++i) tmp[i] = f2bf(g2_W1a[(seg*8 + i)*32 + n]);
        *(short8*)&w1aT[n*HS + seg*8] = *(short8*)tmp;
    }
    if (t < 160) {
        *(float4*)(xb + t*4) = *(const float4*)(x0 + (size_t)b*MM + t*4);
        g1w0a[t] = g1_W0a[t];
        g1w1a[t] = g1_W1a[t];
        w0a2b[t] = g2_W0a[KK*32 + t];
        w1a2b[t] = g2_W1a[KK*32 + t];
        w0b2[t]  = g2_W0b[t];
        w1b2[t]  = g2_W1b[t];
    }
    if (t < 64) { g1w0b[t] = g1_W0b[t]; g1w1b[t] = g1_W1b[t]; }
    __syncthreads();

    // ---------- phase 1: SX = HW@X1 (MFMA) + colsum partials ----------
    {
        floatx4 acc = {0.f, 0.f, 0.f, 0.f};
        const int ns = lr < 5 ? lr : 4;
        #pragma unroll
        for (int kt = 0; kt < 4; ++kt) {
            float4 f0 = *(const float4*)(xb + ns*KK + kt*32 + quad*8);
            float4 f1 = *(const float4*)(xb + ns*KK + kt*32 + quad*8 + 4);
            short8 bb;
            bb[0]=(short)f2bf(f0.x); bb[1]=(short)f2bf(f0.y); bb[2]=(short)f2bf(f0.z); bb[3]=(short)f2bf(f0.w);
            bb[4]=(short)f2bf(f1.x); bb[5]=(short)f2bf(f1.y); bb[6]=(short)f2bf(f1.z); bb[7]=(short)f2bf(f1.w);
            acc = __builtin_amdgcn_mfma_f32_16x16x32_bf16(A[kt], bb, acc, 0, 0, 0);
        }
        if (lr < 5) {
            #pragma unroll
            for (int r = 0; r < 4; ++r)
                scr8[(wv*16 + quad*4 + r)*8 + lr] = acc[r];
        }
    }
    #pragma unroll
    for (int kt = 0; kt < 4; ++kt) {            // colsum: reduce rows over lr within quad
        float v[8];
        #pragma unroll
        for (int j = 0; j < 8; ++j) v[j] = bf2f((unsigned short)A[kt][j]);
        #pragma unroll
        for (int mk = 1; mk < 16; mk <<= 1)
            #pragma unroll
            for (int j = 0; j < 8; ++j) v[j] += __shfl_xor(v[j], mk);
        if (lr == 0) {
            float4 a0 = {v[0],v[1],v[2],v[3]}, a1 = {v[4],v[5],v[6],v[7]};
            *(float4*)&colred[wv*128 + kt*32 + quad*8]     = a0;
            *(float4*)&colred[wv*128 + kt*32 + quad*8 + 4] = a1;
        }
    }
    __syncthreads();

    const int row = t >> 2, g = t & 3;          // 4 lanes per row for row-ops

    // ---------- phase 2: g1 -> per-wave partials ----------
    {
        float sx[5], x1r[5];
        #pragma unroll
        for (int f = 0; f < 5; ++f) { sx[f] = scr8[row*8 + f]; x1r[f] = xb[f*KK + row]; }

        float zb0p0=0, zb0p1=0, zb1p0=0, zb1p1=0;
        #pragma unroll
        for (int hh = 0; hh < 8; ++hh) {
            int h = 8*g + hh;
            float a = 0.0f;
            #pragma unroll
            for (int f = 0; f < 5; ++f) a += x1r[f]*g1w0a[f*32+h] + sx[f]*g1w1a[f*32+h];
            a = fmaxf(a, 0.0f);
            zb0p0 += a * g1w0b[h*2+0];
            zb0p1 += a * g1w0b[h*2+1];
            zb1p0 += a * g1w1b[h*2+0];
            zb1p1 += a * g1w1b[h*2+1];
        }
        float msum = colred[(2*g)*128 + row] + colred[(2*g+1)*128 + row];
        msum += __shfl_xor(msum, 1); msum += __shfl_xor(msum, 2);
        float m = msum * (1.0f/KK);
        float c0 = zb0p0*(1.0f/KK) + m*zb1p0;
        float c1 = zb0p1*(1.0f/KK) + m*zb1p1;
        #pragma unroll
        for (int s = 1; s < 64; s <<= 1) { c0 += __shfl_xor(c0, s); c1 += __shfl_xor(c1, s); }
        if ((t & 63) == 0) { red[wv*2] = c0; red[wv*2 + 1] = c1; }
    }
    __syncthreads();

    // ---------- phase 3: lbd (redundant per-thread) + x update ----------
    {
        float lbd0 = 0.f, lbd1 = 0.f;
        #pragma unroll
        for (int w2 = 0; w2 < 8; ++w2) { lbd0 += red[w2*2]; lbd1 += red[w2*2+1]; }
        lbd0 = fmaxf(lbd0, 0.0f); lbd1 = fmaxf(lbd1, 0.0f);
        if (t < KK) {
            float s1v = xb[KK + t];
            xb[KK + t]   = s1v - lbd0 * (ALPHA / (1.0f + s1v));
            xb[4*KK + t] += lbd1 * (ALPHA * VARTHETA);
        }
    }
    __syncthreads();   // also orders: colred reads (ph2) before c2T writes (ph4)

    // ---------- phase 4: MFMA1: C2 = W0a_top + X2@W1a_bot + HW@W1a_top -> c2T ----------
    #pragma unroll
    for (int nt = 0; nt < 2; ++nt) {
        floatx4 acc = {0.f, 0.f, 0.f, 0.f};
        #pragma unroll
        for (int kt = 0; kt < 4; ++kt) {
            short8 bb = *(const short8*)&w1aT[(nt*16 + lr)*HS + kt*32 + quad*8];
            acc = __builtin_amdgcn_mfma_f32_16x16x32_bf16(A[kt], bb, acc, 0, 0, 0);
        }
        const int n = nt*16 + lr;
        unsigned short pe[4];
        #pragma unroll
        for (int r = 0; r < 4; ++r) {
            int mm = wv*16 + quad*4 + r;
            float v = acc[r] + g2_W0a[mm*32 + n];
            #pragma unroll
            for (int f = 0; f < 5; ++f) v += xb[f*KK + mm] * w1a2b[f*32 + n];
            pe[r] = f2bf(v);
        }
        ushort4 p4; p4.x = pe[0]; p4.y = pe[1]; p4.z = pe[2]; p4.w = pe[3];
        *(ushort4*)&c2T[n*HS + wv*16 + quad*4] = p4;
    }
    __syncthreads();   // orders: c2T write->read AND w1aT read (ph4) -> zbp write (ph5)

    // ---------- phase 5: MFMA2: Z = relu(HW@C2 + X2@W0a_bot) -> zb ----------
    #pragma unroll
    for (int nt = 0; nt < 2; ++nt) {
        floatx4 acc = {0.f, 0.f, 0.f, 0.f};
        #pragma unroll
        for (int kt = 0; kt < 4; ++kt) {
            short8 bb = *(const short8*)&c2T[(nt*16 + lr)*HS + kt*32 + quad*8];
            acc = __builtin_amdgcn_mfma_f32_16x16x32_bf16(A[kt], bb, acc, 0, 0, 0);
        }
        const int n = nt*16 + lr;
        #pragma unroll
        for (int r = 0; r < 4; ++r) {
            int mm = wv*16 + quad*4 + r;
            float v = acc[r];
            #pragma unroll
            for (int f = 0; f < 5; ++f) v += xb[f*KK + mm] * w0a2b[f*32 + n];
            zbp[mm*ZSS + n] = f2bf(fmaxf(v, 0.0f));
        }
    }
    __syncthreads();

    // ---------- phase 6: E = Z@W1b2 -> eT, t0 = Z@W0b2 -> scr8 ----------
    {
        float ev[5] = {0,0,0,0,0}, t0v[5] = {0,0,0,0,0};
        short8 zrow = *(const short8*)&zbp[row*ZSS + g*8];
        #pragma unroll
        for (int hh = 0; hh < 8; ++hh) {
            int h = 8*g + hh;
            float zv = bf2f((unsigned short)zrow[hh]);
            #pragma unroll
            for (int c = 0; c < 5; ++c) {
                ev[c]  += zv * w1b2[h*5 + c];
                t0v[c] += zv * w0b2[h*5 + c];
            }
        }
        #pragma unroll
        for (int c = 0; c < 5; ++c) {
            ev[c]  += __shfl_xor(ev[c], 1);  ev[c]  += __shfl_xor(ev[c], 2);
            t0v[c] += __shfl_xor(t0v[c], 1); t0v[c] += __shfl_xor(t0v[c], 2);
        }
        if (g == 0) {
            #pragma unroll
            for (int c = 0; c < 5; ++c) {
                eT[c*HS + row]  = f2bf(ev[c]);
                scr8[row*8 + c] = t0v[c];
            }
        }
    }
    __syncthreads();

    // ---------- phase 7: tilde = t0 + HW@E ; x += tilde^T ----------
    {
        floatx4 acc = {0.f, 0.f, 0.f, 0.f};
        const int ns = lr < 5 ? lr : 4;
        #pragma unroll
        for (int kt = 0; kt < 4; ++kt) {
            short8 bb = *(const short8*)&eT[ns*HS + kt*32 + quad*8];
            acc = __builtin_amdgcn_mfma_f32_16x16x32_bf16(A[kt], bb, acc, 0, 0, 0);
        }
        if (lr < 5) {
            #pragma unroll
            for (int r = 0; r < 4; ++r) {
                int mm = wv*16 + quad*4 + r;
                xb[lr*KK + mm] += acc[r] + scr8[mm*8 + lr];
            }
        }
    }
    __syncthreads();

    // ---------- phase 8: f = sum(x[:K]) - PMAX (redundant per-thread) ----------
    float pv = (t < KK) ? xb[t] : 0.0f;
    #pragma unroll
    for (int s = 1; s < 64; s <<= 1) pv += __shfl_xor(pv, s);
    if ((t & 63) == 0) red[wv] = pv;
    __syncthreads();
    float fv = -PMAXV;
    #pragma unroll
    for (int w2 = 0; w2 < 8; ++w2) fv += red[w2];

    const int num_itr = num_itr_p[0], kth = kth_p[0];
    const bool flag = (kth == num_itr - 1);
    const float nu3 = nu3_p[0], tg = tg_p[0];
    const float onu = 1.0f + nu3, otg = 1.0f + tg;
    const float Vnu = 1.0f - 1.0f/(onu*onu), Vg = 1.0f - 1.0f/(otg*otg);
    float* outx = out + (size_t)b * MM;

    // ---------- phase 9: clamp + store ----------
    #pragma unroll
    for (int r2 = 0; r2 < 2; ++r2) {
        int idx = r2*512 + t;
        if (idx < MM) {
            float v = xb[idx];
            if (idx < KK && fv > 0.0f) v -= fv * (1.0f/KK);
            v = fmaxf(v, (idx >= KK   && idx < 2*KK) ? nu3 : 0.0f);
            v = fminf(v, (idx >= 2*KK && idx < 3*KK) ? tg  : BIGV);
            v = fmaxf(v, (idx >= 3*KK && idx < 4*KK) ? Vnu : 0.0f);
            v = fminf(v, (idx >= 3*KK && idx < 4*KK) ? Vg  : BIGV);
            if (flag) v = fmaxf(v, 0.0f);
            xb[idx] = v;
            outx[idx] = v;
        }
    }

    // ---------- phase 10: extra outputs (last iteration) ----------
    if (flag) {
        __syncthreads();
        const size_t O1 = (size_t)B_N*MM;
        const size_t OK = (size_t)B_N*KK;
        if (t < KK) {
            float xg = xb[2*KK + t], xv = xb[3*KK + t];
            float u1 = 1.0f + xg;
            out[O1 + (size_t)b*KK + t]      = 1.0f - 1.0f/(u1*u1) - xv;   // f5
            out[O1 + OK + (size_t)b*KK + t] = sqrtf(xv) - xb[4*KK + t];   // f6
        }
        {   // diag extract from A-fragments
            int kt_n = wv >> 1;
            int qexp = ((wv & 1) << 1) + (lr >> 3);
            if (quad == qexp) {
                short8 av = A[0];
                if (kt_n == 1) av = A[1];
                else if (kt_n == 2) av = A[2];
                else if (kt_n == 3) av = A[3];
                int j = lr & 7;
                float dv = 0.f;
                #pragma unroll
                for (int jj = 0; jj < 8; ++jj) if (jj == j) dv = bf2f((unsigned short)av[jj]);
                diagl[arow] = dv;
            }
        }
        {   // dp = p @ HW partials via shfl
            float p = xb[arow];
            #pragma unroll
            for (int kt = 0; kt < 4; ++kt) {
                float v[8];
                #pragma unroll
                for (int j = 0; j < 8; ++j) v[j] = p * bf2f((unsigned short)A[kt][j]);
                #pragma unroll
                for (int mk = 1; mk < 16; mk <<= 1)
                    #pragma unroll
                    for (int j = 0; j < 8; ++j) v[j] += __shfl_xor(v[j], mk);
                if (lr == 0) {
                    float4 a0 = {v[0],v[1],v[2],v[3]}, a1 = {v[4],v[5],v[6],v[7]};
                    *(float4*)&dpred[wv*128 + kt*32 + quad*8]     = a0;
                    *(float4*)&dpred[wv*128 + kt*32 + quad*8 + 4] = a1;
                }
            }
        }
        __syncthreads();
        {   // combine dp per row, emit f4/f2
            float ds = dpred[(2*g)*128 + row] + dpred[(2*g+1)*128 + row];
            ds += __shfl_xor(ds, 1); ds += __shfl_xor(ds, 2);
            if (g == 0) {
                float p_  = xb[row], nuv = xb[KK + row], xg = xb[2*KK + row];
                float top = p_ * diagl[row];
                float down = ds - top + 1.0f;
                out[O1 + 2*OK + (size_t)b*KK + row] = top - down * xg;    // f4
                out[O1 + 3*OK + (size_t)b*KK + row] = nuv * down - top;   // f2
            }
        }
    }
}

extern "C" void kernel_launch(void* const* d_in, const int* in_sizes, int n_in,
                              void* d_out, int out_size, void* d_ws, size_t ws_size,
                              hipStream_t stream) {
    unfold_pocs_kernel<<<dim3(B_N), dim3(512), 0, stream>>>(
        (const int*)d_in[0], (const int*)d_in[1],
        (const float*)d_in[2], (const float*)d_in[3],
        (const float*)d_in[4], (const float*)d_in[5],
        (const float*)d_in[12], (const float*)d_in[13],
        (const float*)d_in[14], (const float*)d_in[15],
        (const float*)d_in[16], (const float*)d_in[17],
        (const float*)d_in[18], (const float*)d_in[19],
        (float*)d_out);
}

// Round 5
// 252.843 us; speedup vs baseline: 1.5252x; 1.5252x over previous
//
#include <hip/hip_runtime.h>
#include <math.h>

#define B_N 2048
#define KK 128
#define MM 640
#define HS 136    // k-stride (elems) for bf16 panels (mult of 8 for b128 align, breaks pow2 banks)
#define ZSS 40    // Z row stride (bf16)
#define SXS 12    // SX row stride (fp32)
#define ALPHA (1.0f/128.0f)
#define VARTHETA 0.1f
#define PMAXV 10.0f
#define BIGV 1000000000.0f

typedef __attribute__((ext_vector_type(8))) short short8;
typedef __attribute__((ext_vector_type(4))) short short4v;
typedef __attribute__((ext_vector_type(4))) float floatx4;
typedef __attribute__((ext_vector_type(4))) __bf16 bf16x4;

static __device__ __forceinline__ unsigned short f2bf(float f) {
    return __builtin_bit_cast(unsigned short, (__bf16)f);   // RNE, v_cvt on gfx950
}
static __device__ __forceinline__ short4v cvt4(floatx4 v) {
    return __builtin_bit_cast(short4v, __builtin_convertvector(v, bf16x4));
}
static __device__ __forceinline__ float bf2f(unsigned short h) {
    unsigned u = ((unsigned)h) << 16;
    return __builtin_bit_cast(float, u);
}

// LDS pool overlays (time-sliced):
//  poolA (10240 B): w1aT (32x136 bf16, staging->MFMA1)  then  zbp (128x40 bf16, MFMA2->E)
//  poolB (8704 B) : SXs (128x12 f32, ph1->ph2) -> c2T (32x136 bf16, MFMA1->MFMA2)
//                   -> eT (5x136 bf16 @0) + t0f (128x8 f32 @2048)  (ph6->ph7)
#define POOLA_OFF 0
#define POOLB_OFF 10240
#define POOL_BYTES (10240 + 8704)

// (512,4) with R2-style short register live-ranges: VGPR=64, no spill (R2-proven).
// R3/R4's persistent global-loaded A-fragments caused 200-300MB scratch spill; hw stays in LDS.
__global__ __launch_bounds__(512, 4)
void unfold_pocs_kernel(
    const int* __restrict__ num_itr_p, const int* __restrict__ kth_p,
    const float* __restrict__ HW, const float* __restrict__ x0,
    const float* __restrict__ nu3_p, const float* __restrict__ tg_p,
    const float* __restrict__ g1_W0a, const float* __restrict__ g1_W1a,
    const float* __restrict__ g1_W0b, const float* __restrict__ g1_W1b,
    const float* __restrict__ g2_W0a, const float* __restrict__ g2_W1a,
    const float* __restrict__ g2_W0b, const float* __restrict__ g2_W1b,
    float* __restrict__ out)
{
    __shared__ __align__(16) unsigned short hwb[KK*HS];     // 34816 B, bf16 hw row-major
    __shared__ __align__(16) unsigned char pool[POOL_BYTES];
    __shared__ __align__(16) float xb[MM];                  // 2560 B
    __shared__ __align__(16) unsigned short xbf[5*HS];      // 1360 B, X1 bf16 [f][k]
    __shared__ __align__(16) unsigned short x2bf[KK*8];     // 2048 B, X2 bf16 [m][f(0..7 pad)]
    __shared__ __align__(16) unsigned short w1abf[32*8];    // 512 B, W1a_bot [n][k pad]
    __shared__ __align__(16) unsigned short w0abf[32*8];    // 512 B, W0a_bot [n][k pad]
    __shared__ __align__(16) float g1w0a[160], g1w1a[160];
    __shared__ __align__(16) float g1w0b[64],  g1w1b[64];
    __shared__ __align__(16) float w0b2[160],  w1b2[160];   // 32x5 f32
    __shared__ float red[16];

    unsigned short* w1aT = (unsigned short*)(pool + POOLA_OFF);
    unsigned short* zbp  = (unsigned short*)(pool + POOLA_OFF);
    float*          SXs  = (float*)(pool + POOLB_OFF);
    unsigned short* c2T  = (unsigned short*)(pool + POOLB_OFF);
    unsigned short* eT   = (unsigned short*)(pool + POOLB_OFF);
    float*          t0f  = (float*)(pool + POOLB_OFF + 2048);

    const int t = threadIdx.x;
    const int b = blockIdx.x;
    const float* HWb = HW + (size_t)b * (KK*KK);

    const int wv = t >> 6, lane = t & 63, quad = lane >> 4, lr = lane & 15;
    const int arow = wv*16 + lr;

    // ---------- staging ----------
    #pragma unroll
    for (int it = 0; it < 8; ++it) {            // hw -> bf16 LDS
        int qi = it * 512 + t;                  // 4096 float4-quads
        int row = qi >> 5, q = qi & 31;
        floatx4 v = *(const floatx4*)(HWb + row*KK + q*4);
        *(short4v*)&hwb[row*HS + q*4] = cvt4(v);
    }
    {   // W1a_top (128x32) -> transposed bf16 [n][k]
        const int n = t & 31, seg = t >> 5;     // 16 segs of 8 k
        unsigned short tmp[8];
        #pragma unroll
        for (int i = 0; i < 8; ++i) tmp[i] = f2bf(g2_W1a[(seg*8 + i)*32 + n]);
        *(short8*)&w1aT[n*HS + seg*8] = *(short8*)tmp;
    }
    {   // W1a_bot / W0a_bot (5x32) -> [n][k0..7], zero-padded
        const int n = (t & 255) >> 3, j = t & 7;
        if (t < 256) w1abf[t]       = (j < 5) ? f2bf(g2_W1a[(KK + j)*32 + n]) : (unsigned short)0;
        else if (t < 512) w0abf[t - 256] = (j < 5) ? f2bf(g2_W0a[(KK + j)*32 + n]) : (unsigned short)0;
    }
    if (t < 160) {
        floatx4 v = *(const floatx4*)(x0 + (size_t)b*MM + t*4);
        *(floatx4*)(xb + t*4) = v;
        *(short4v*)&xbf[(t >> 5)*HS + ((t*4) & 127)] = cvt4(v);   // X1 bf16 copy
        g1w0a[t] = g1_W0a[t];
        g1w1a[t] = g1_W1a[t];
        w0b2[t]  = g2_W0b[t];
        w1b2[t]  = g2_W1b[t];
    }
    if (t < 64) { g1w0b[t] = g1_W0b[t]; g1w1b[t] = g1_W1b[t]; }
    __syncthreads();

    // ---------- phase 1: SX = HW@X1 (MFMA, B from xbf) ----------
    {
        floatx4 acc = {0.f, 0.f, 0.f, 0.f};
        const int ns = lr < 5 ? lr : 4;
        #pragma unroll
        for (int kt = 0; kt < 4; ++kt) {
            short8 a  = *(const short8*)&hwb[arow*HS + kt*32 + quad*8];
            short8 bb = *(const short8*)&xbf[ns*HS   + kt*32 + quad*8];
            acc = __builtin_amdgcn_mfma_f32_16x16x32_bf16(a, bb, acc, 0, 0, 0);
        }
        if (lr < 5) {
            #pragma unroll
            for (int r = 0; r < 4; ++r)
                SXs[(wv*16 + quad*4 + r)*SXS + lr] = acc[r];
        }
    }
    __syncthreads();

    const int row = t >> 2, g = t & 3;          // 4 lanes per row for row-ops

    // ---------- phase 2: g1 -> per-wave partials ----------
    {
        float sx[5], x1r[5];
        #pragma unroll
        for (int f = 0; f < 5; ++f) { sx[f] = SXs[row*SXS + f]; x1r[f] = xb[f*KK + row]; }

        float zb0p0=0, zb0p1=0, zb1p0=0, zb1p1=0;
        #pragma unroll
        for (int hh = 0; hh < 8; ++hh) {
            int h = 8*g + hh;
            float a = 0.0f;
            #pragma unroll
            for (int f = 0; f < 5; ++f) a += x1r[f]*g1w0a[f*32+h] + sx[f]*g1w1a[f*32+h];
            a = fmaxf(a, 0.0f);
            zb0p0 += a * g1w0b[h*2+0];
            zb0p1 += a * g1w0b[h*2+1];
            zb1p0 += a * g1w1b[h*2+0];
            zb1p1 += a * g1w1b[h*2+1];
        }
        float mp = 0.0f;                        // colsum of hw column 'row'
        for (int w = 0; w < 32; ++w) {
            int i = 4*w + g;
            mp += bf2f(hwb[i*HS + row]);
        }
        mp += __shfl_xor(mp, 1); mp += __shfl_xor(mp, 2);
        float m = mp * (1.0f/KK);
        float c0 = zb0p0*(1.0f/KK) + m*zb1p0;
        float c1 = zb0p1*(1.0f/KK) + m*zb1p1;
        #pragma unroll
        for (int s = 1; s < 64; s <<= 1) { c0 += __shfl_xor(c0, s); c1 += __shfl_xor(c1, s); }
        if (lane == 0) { red[wv*2] = c0; red[wv*2 + 1] = c1; }
    }
    __syncthreads();

    // ---------- phase 3: lbd (redundant) + x update + x2bf build (race-free) ----------
    {
        float lbd0 = 0.f, lbd1 = 0.f;
        #pragma unroll
        for (int w2 = 0; w2 < 8; ++w2) { lbd0 += red[w2*2]; lbd1 += red[w2*2+1]; }
        lbd0 = fmaxf(lbd0, 0.0f); lbd1 = fmaxf(lbd1, 0.0f);

        const int i0 = 2*t, m = i0 >> 3, f0 = i0 & 7;     // f0 in {0,2,4,6}
        float va = (f0     < 5) ? xb[f0*KK + m]     : 0.f;
        float vb = (f0 + 1 < 5) ? xb[(f0+1)*KK + m] : 0.f;
        if (f0 == 0) { vb = vb - lbd0 * (ALPHA / (1.0f + vb)); xb[KK + m]   = vb; }
        if (f0 == 4) { va = va + lbd1 * (ALPHA * VARTHETA);    xb[4*KK + m] = va; }
        ushort2 p; p.x = f2bf(va); p.y = f2bf(vb);
        *(ushort2*)&x2bf[i0] = p;
    }
    __syncthreads();

    // ---------- A-fragments from LDS (live ph4-ph7 only; R2-proven pressure) ----------
    short8 A[4];
    #pragma unroll
    for (int kt = 0; kt < 4; ++kt)
        A[kt] = *(const short8*)&hwb[arow*HS + kt*32 + quad*8];

    // ---------- phase 4: MFMA1: C2 = W0a_top + X2@W1a_bot + HW@W1a_top -> c2T ----------
    #pragma unroll
    for (int nt = 0; nt < 2; ++nt) {
        const int n = nt*16 + lr, mmb = wv*16 + quad*4;
        floatx4 acc = {0.f, 0.f, 0.f, 0.f};
        short8 ax2 = {0,0,0,0,0,0,0,0}, bx2 = {0,0,0,0,0,0,0,0};
        if (quad == 0) {
            ax2 = *(const short8*)&x2bf[(wv*16 + lr)*8];
            bx2 = *(const short8*)&w1abf[n*8];
        }
        acc = __builtin_amdgcn_mfma_f32_16x16x32_bf16(ax2, bx2, acc, 0, 0, 0);
        #pragma unroll
        for (int kt = 0; kt < 4; ++kt) {
            short8 bb = *(const short8*)&w1aT[n*HS + kt*32 + quad*8];
            acc = __builtin_amdgcn_mfma_f32_16x16x32_bf16(A[kt], bb, acc, 0, 0, 0);
        }
        ushort4 pe;
        pe.x = f2bf(acc[0] + g2_W0a[(mmb+0)*32 + n]);
        pe.y = f2bf(acc[1] + g2_W0a[(mmb+1)*32 + n]);
        pe.z = f2bf(acc[2] + g2_W0a[(mmb+2)*32 + n]);
        pe.w = f2bf(acc[3] + g2_W0a[(mmb+3)*32 + n]);
        *(ushort4*)&c2T[n*HS + mmb] = pe;
    }
    __syncthreads();

    // ---------- phase 5: MFMA2: Z = relu(HW@C2 + X2@W0a_bot) -> zbp ----------
    #pragma unroll
    for (int nt = 0; nt < 2; ++nt) {
        const int n = nt*16 + lr, mmb = wv*16 + quad*4;
        floatx4 acc = {0.f, 0.f, 0.f, 0.f};
        short8 ax2 = {0,0,0,0,0,0,0,0}, bx2 = {0,0,0,0,0,0,0,0};
        if (quad == 0) {
            ax2 = *(const short8*)&x2bf[(wv*16 + lr)*8];
            bx2 = *(const short8*)&w0abf[n*8];
        }
        acc = __builtin_amdgcn_mfma_f32_16x16x32_bf16(ax2, bx2, acc, 0, 0, 0);
        #pragma unroll
        for (int kt = 0; kt < 4; ++kt) {
            short8 bb = *(const short8*)&c2T[n*HS + kt*32 + quad*8];
            acc = __builtin_amdgcn_mfma_f32_16x16x32_bf16(A[kt], bb, acc, 0, 0, 0);
        }
        #pragma unroll
        for (int r = 0; r < 4; ++r)
            zbp[(mmb + r)*ZSS + n] = f2bf(fmaxf(acc[r], 0.0f));
    }
    __syncthreads();

    // ---------- phase 6: E = Z@W1b2 -> eT, t0 = Z@W0b2 -> t0f ----------
    {
        float ev[5] = {0,0,0,0,0}, t0v[5] = {0,0,0,0,0};
        short8 zrow = *(const short8*)&zbp[row*ZSS + g*8];
        #pragma unroll
        for (int hh = 0; hh < 8; ++hh) {
            int h = 8*g + hh;
            float zv = bf2f((unsigned short)zrow[hh]);
            #pragma unroll
            for (int c = 0; c < 5; ++c) {
                ev[c]  += zv * w1b2[h*5 + c];
                t0v[c] += zv * w0b2[h*5 + c];
            }
        }
        #pragma unroll
        for (int c = 0; c < 5; ++c) {
            ev[c]  += __shfl_xor(ev[c], 1);  ev[c]  += __shfl_xor(ev[c], 2);
            t0v[c] += __shfl_xor(t0v[c], 1); t0v[c] += __shfl_xor(t0v[c], 2);
        }
        if (g == 0) {
            #pragma unroll
            for (int c = 0; c < 5; ++c) {
                eT[c*HS + row]  = f2bf(ev[c]);
                t0f[row*8 + c]  = t0v[c];
            }
        }
    }
    __syncthreads();

    // ---------- phase 7: tilde = t0 + HW@E ; x += tilde^T ----------
    {
        floatx4 acc = {0.f, 0.f, 0.f, 0.f};
        const int ns = lr < 5 ? lr : 4;
        #pragma unroll
        for (int kt = 0; kt < 4; ++kt) {
            short8 bb = *(const short8*)&eT[ns*HS + kt*32 + quad*8];
            acc = __builtin_amdgcn_mfma_f32_16x16x32_bf16(A[kt], bb, acc, 0, 0, 0);
        }
        if (lr < 5) {
            #pragma unroll
            for (int r = 0; r < 4; ++r) {
                int mm = wv*16 + quad*4 + r;
                xb[lr*KK + mm] += acc[r] + t0f[mm*8 + lr];
            }
        }
    }
    __syncthreads();

    // ---------- phase 8: f = sum(x[:K]) - PMAX (redundant per-thread) ----------
    float pv = (t < KK) ? xb[t] : 0.0f;
    #pragma unroll
    for (int s = 1; s < 64; s <<= 1) pv += __shfl_xor(pv, s);
    if (lane == 0) red[wv] = pv;
    __syncthreads();
    float fv = -PMAXV;
    #pragma unroll
    for (int w2 = 0; w2 < 8; ++w2) fv += red[w2];

    const int num_itr = num_itr_p[0], kth = kth_p[0];
    const bool flag = (kth == num_itr - 1);
    const float nu3 = nu3_p[0], tg = tg_p[0];
    const float onu = 1.0f + nu3, otg = 1.0f + tg;
    const float Vnu = 1.0f - 1.0f/(onu*onu), Vg = 1.0f - 1.0f/(otg*otg);
    float* outx = out + (size_t)b * MM;

    // ---------- phase 9: clamp + store ----------
    #pragma unroll
    for (int r2 = 0; r2 < 2; ++r2) {
        int idx = r2*512 + t;
        if (idx < MM) {
            float v = xb[idx];
            if (idx < KK && fv > 0.0f) v -= fv * (1.0f/KK);
            v = fmaxf(v, (idx >= KK   && idx < 2*KK) ? nu3 : 0.0f);
            v = fminf(v, (idx >= 2*KK && idx < 3*KK) ? tg  : BIGV);
            v = fmaxf(v, (idx >= 3*KK && idx < 4*KK) ? Vnu : 0.0f);
            v = fminf(v, (idx >= 3*KK && idx < 4*KK) ? Vg  : BIGV);
            if (flag) v = fmaxf(v, 0.0f);
            xb[idx] = v;
            outx[idx] = v;
        }
    }

    // ---------- phase 10: extra outputs (last iteration) ----------
    if (flag) {
        __syncthreads();
        const size_t O1 = (size_t)B_N*MM;
        const size_t OK = (size_t)B_N*KK;
        if (t < KK) {
            float xg = xb[2*KK + t], xv = xb[3*KK + t];
            float u1 = 1.0f + xg;
            out[O1 + (size_t)b*KK + t]      = 1.0f - 1.0f/(u1*u1) - xv;   // f5
            out[O1 + OK + (size_t)b*KK + t] = sqrtf(xv) - xb[4*KK + t];   // f6
        }
        float dp = 0.0f;    // sum_i p[i]*hw[i][col=row]
        for (int w = 0; w < 32; ++w) {
            int i = 4*w + g;
            dp += xb[i] * bf2f(hwb[i*HS + row]);
        }
        dp += __shfl_xor(dp, 1); dp += __shfl_xor(dp, 2);
        if (g == 0) {
            float p_  = xb[row], nuv = xb[KK + row], xg = xb[2*KK + row];
            float diag = bf2f(hwb[row*HS + row]);
            float top  = p_ * diag;
            float down = dp - top + 1.0f;
            out[O1 + 2*OK + (size_t)b*KK + row] = top - down * xg;        // f4
            out[O1 + 3*OK + (size_t)b*KK + row] = nuv * down - top;       // f2
        }
    }
}

extern "C" void kernel_launch(void* const* d_in, const int* in_sizes, int n_in,
                              void* d_out, int out_size, void* d_ws, size_t ws_size,
                              hipStream_t stream) {
    unfold_pocs_kernel<<<dim3(B_N), dim3(512), 0, stream>>>(
        (const int*)d_in[0], (const int*)d_in[1],
        (const float*)d_in[2], (const float*)d_in[3],
        (const float*)d_in[4], (const float*)d_in[5],
        (const float*)d_in[12], (const float*)d_in[13],
        (const float*)d_in[14], (const float*)d_in[15],
        (const float*)d_in[16], (const float*)d_in[17],
        (const float*)d_in[18], (const float*)d_in[19],
        (float*)d_out);
}